// Round 9
// baseline (525.567 us; speedup 1.0000x reference)
//
#include <hip/hip_runtime.h>
#include <hip/hip_fp16.h>

// Per-point expert-indexed MLP: h = LeakyReLU(h @ W[idx] + b[idx]) x3.
//
// R18 = R17 with the scheduler UNLEASHED (single-variable experiment).
// R17 post-mortem: dur ~invariant across 4x LDS-traffic and 2x occupancy
// changes (R13 55us / R15 50us / R17 58us), VALUBusy pinned 17-21% -> the
// limiter is the phase fences (sched_barrier(0)) + unroll-1 serializing
// ds_read issue: each phase pays exposed ~120cyc LDS latency per chunk.
// The fences were R14 spill containment; R17 is at 52 VGPR vs 128 cap ->
// huge headroom. Change: remove ALL MLP-body fences + fully unroll the
// ch loop. Everything else byte-identical to R17 (passed, absmax 0.125).
// Spill tripwire: WRITE_SIZE must stay ~31 MB; balloon = spill = revert.

#define L_EXP 16
#define IN0   7
#define C0    16
#define C1    32
#define C2    16
#define NEG   0.2f
#define BLK   256
#define PPB   496         // points per block; padded slots <= 496+16 = 512

typedef _Float16 h2 __attribute__((ext_vector_type(2)));
union F4H { float4 f4; h2 h[4]; };

__device__ __forceinline__ h2 pk(float a, float b) {
    return __builtin_bit_cast(h2, __builtin_amdgcn_cvt_pkrtz(a, b));
}
__device__ __forceinline__ float leaky(float a) { return fmaxf(a, NEG * a); }
__device__ __forceinline__ float fdot2(h2 a, h2 b, float c) {
    return __builtin_amdgcn_fdot2(a, b, c, false);
}

__global__ void __launch_bounds__(BLK, 4) k_fused(
    const float* __restrict__ x, const int* __restrict__ idx,
    const float* __restrict__ W0, const float* __restrict__ b0,
    const float* __restrict__ W1, const float* __restrict__ b1,
    const float* __restrict__ W2, const float* __restrict__ b2,
    float* __restrict__ out, int n) {
    // expert-innermost fp16 weight tiles; 16 B per (row, expert)
    __shared__ __align__(16) __half sW0[C0 * L_EXP * 8];      // [o][e][8]  4 KB
    __shared__ __align__(16) __half sW1[C1 * 2 * L_EXP * 8];  // [o][q2][e][8] 16 KB
    __shared__ __align__(16) __half sW2[C2 * 4 * L_EXP * 8];  // [o][q4][e][8] 16 KB
    __shared__ __half sB1h[C1 * L_EXP];                       // [o][e] 1 KB
    __shared__ __half sB2h[C2 * L_EXP];                       // [o][e] 512 B
    __shared__ unsigned short spid[512];                      // (e<<10)|local, 1 KB
    __shared__ int bins[L_EXP];
    __shared__ int poff[L_EXP];

    int t = threadIdx.x;

    // ---- stage all experts' weights (once per block; proven R13 code) ----
    {   // W0: 256 rows of 8 halves; row k: o=k>>4, e=k&15; c=0..6 + bias slot
        int o = t >> 4, e = t & 15;
        float v0 = W0[e * (IN0 * C0) + 0 * C0 + o];
        float v1 = W0[e * (IN0 * C0) + 1 * C0 + o];
        float v2 = W0[e * (IN0 * C0) + 2 * C0 + o];
        float v3 = W0[e * (IN0 * C0) + 3 * C0 + o];
        float v4 = W0[e * (IN0 * C0) + 4 * C0 + o];
        float v5 = W0[e * (IN0 * C0) + 5 * C0 + o];
        float v6 = W0[e * (IN0 * C0) + 6 * C0 + o];
        float v7 = b0[e * C0 + o];           // bias via x7=1.0
        F4H u;
        u.h[0] = pk(v0, v1); u.h[1] = pk(v2, v3);
        u.h[2] = pk(v4, v5); u.h[3] = pk(v6, v7);
        reinterpret_cast<float4*>(sW0)[t] = u.f4;
    }
#pragma unroll
    for (int rr = 0; rr < 4; ++rr) {  // W1: 1024 rows; row r=(o*2+q2)*16+e
        int r = rr * BLK + t;
        int o = r >> 5, q = (r >> 4) & 1, e = r & 15;
        const float* wp = W1 + e * (C0 * C1) + (q * 8) * C1 + o;
        F4H u;
#pragma unroll
        for (int j = 0; j < 4; ++j)
            u.h[j] = pk(wp[(2 * j) * C1], wp[(2 * j + 1) * C1]);
        reinterpret_cast<float4*>(sW1)[r] = u.f4;
    }
#pragma unroll
    for (int rr = 0; rr < 4; ++rr) {  // W2: 1024 rows; row r=(o*4+q4)*16+e
        int r = rr * BLK + t;
        int o = r >> 6, q = (r >> 4) & 3, e = r & 15;
        const float* wp = W2 + e * (C1 * C2) + (q * 8) * C2 + o;
        F4H u;
#pragma unroll
        for (int j = 0; j < 4; ++j)
            u.h[j] = pk(wp[(2 * j) * C2], wp[(2 * j + 1) * C2]);
        reinterpret_cast<float4*>(sW2)[r] = u.f4;
    }
    {   // biases [o][e] as fp16
        int o = t >> 4, e = t & 15;
        sB1h[t] = __float2half(b1[e * C1 + o]);            // o 0..15
        int r2 = t + 256; int o2 = r2 >> 4, e2 = r2 & 15;
        sB1h[r2] = __float2half(b1[e2 * C1 + o2]);         // o 16..31
        sB2h[t] = __float2half(b2[e * C2 + o]);
    }
    if (t < L_EXP) bins[t] = 0;
    reinterpret_cast<int*>(spid)[t] = -1;   // all 256 ints = 512 ushorts
    __syncthreads();

    // ---- block-local sort of up to 496 points, expert groups padded to 2 ----
    int base = blockIdx.x * PPB;
    int cnt = n - base; if (cnt > PPB) cnt = PPB;
    int eL[2], rL[2];
    bool vL[2];
    int i2 = t * 2;   // local ids 2t, 2t+1 (threads 248..255 idle: i2 >= 496)
#pragma unroll
    for (int q = 0; q < 2; ++q) {
        int li = i2 + q;
        vL[q] = (li < cnt);
        if (vL[q]) {
            eL[q] = idx[base + li] & 15;
            rL[q] = atomicAdd(&bins[eL[q]], 1);
        }
    }
    __syncthreads();
    if (t < L_EXP) {   // 16-lane scan of pad2 counts
        int c = bins[t];
        int p = (c + 1) & ~1;
        int s = p;
#pragma unroll
        for (int d = 1; d < L_EXP; d <<= 1) {
            int u = __shfl_up(s, d, L_EXP);
            if (t >= d) s += u;
        }
        poff[t] = s - p;
    }
    __syncthreads();
#pragma unroll
    for (int q = 0; q < 2; ++q)
        if (vL[q]) spid[poff[eL[q]] + rL[q]] =
            (unsigned short)((eL[q] << 10) | (i2 + q));
    __syncthreads();

    // ---- thread processes slots 2t, 2t+1 (same expert by construction:
    //      groups start at even offsets, pads only at odd slot positions) ----
    int s0 = (int)spid[2 * t];
    bool any = (s0 != 0xFFFF);
    int e = any ? (s0 >> 10) : 0;
    int l0 = any ? (s0 & 1023) : 0;
    int pid[2]; bool act[2];
#pragma unroll
    for (int q = 0; q < 2; ++q) {
        int sq = (int)spid[2 * t + q];
        act[q] = (sq != 0xFFFF);
        pid[q] = base + (act[q] ? (sq & 1023) : l0);
    }

    const char* w0p = (const char*)sW0 + e * 16;
    const char* w1p = (const char*)sW1 + e * 16;
    const char* w2p = (const char*)sW2 + e * 16;

    h2 xh[2][4];
#pragma unroll
    for (int q = 0; q < 2; ++q) {
        const float* xp = x + (size_t)pid[q] * IN0;
        float4 a = *reinterpret_cast<const float4*>(xp);
        float4 b = *reinterpret_cast<const float4*>(xp + 3);
        xh[q][0] = pk(a.x, a.y);
        xh[q][1] = pk(a.z, a.w);
        xh[q][2] = pk(b.y, b.z);
        xh[q][3] = pk(b.w, 1.0f);   // 1.0 -> bias slot
    }

    // ---- Layer 0: 7(+bias) -> 16, pairwise rows, weights shared by 2 pts ----
    h2 h0h[2][8];
#pragma unroll
    for (int op = 0; op < 8; ++op) {
        F4H ua, ub;
        ua.f4 = *reinterpret_cast<const float4*>(w0p + (2 * op) * 256);
        ub.f4 = *reinterpret_cast<const float4*>(w0p + (2 * op + 1) * 256);
#pragma unroll
        for (int q = 0; q < 2; ++q) {
            float a0 = 0.f, a1 = 0.f;
            a0 = fdot2(xh[q][0], ua.h[0], a0); a1 = fdot2(xh[q][0], ub.h[0], a1);
            a0 = fdot2(xh[q][1], ua.h[1], a0); a1 = fdot2(xh[q][1], ub.h[1], a1);
            a0 = fdot2(xh[q][2], ua.h[2], a0); a1 = fdot2(xh[q][2], ub.h[2], a1);
            a0 = fdot2(xh[q][3], ua.h[3], a0); a1 = fdot2(xh[q][3], ub.h[3], a1);
            h0h[q][op] = pk(leaky(a0), leaky(a1));
        }
    }

    // ---- Layers 1+2 fused; fully unrolled, scheduler free to pipeline ----
    float h2a[2][C2];
#pragma unroll
    for (int q = 0; q < 2; ++q)
#pragma unroll
        for (int o = 0; o < C2; ++o)
            h2a[q][o] = __half2float(sB2h[o * 16 + e]);
#pragma unroll
    for (int ch = 0; ch < 4; ++ch) {   // h1 neurons ch*8 .. ch*8+7
        float tvf[2][8];
#pragma unroll
        for (int o8 = 0; o8 < 8; ++o8) {
            int o = ch * 8 + o8;
            F4H ua, ub;
            ua.f4 = *reinterpret_cast<const float4*>(w1p + (2 * o) * 256);
            ub.f4 = *reinterpret_cast<const float4*>(w1p + (2 * o + 1) * 256);
            float bias = __half2float(sB1h[o * 16 + e]);
#pragma unroll
            for (int q = 0; q < 2; ++q) {
                float a = bias;
                a = fdot2(h0h[q][0], ua.h[0], a);
                a = fdot2(h0h[q][1], ua.h[1], a);
                a = fdot2(h0h[q][2], ua.h[2], a);
                a = fdot2(h0h[q][3], ua.h[3], a);
                a = fdot2(h0h[q][4], ub.h[0], a);
                a = fdot2(h0h[q][5], ub.h[1], a);
                a = fdot2(h0h[q][6], ub.h[2], a);
                a = fdot2(h0h[q][7], ub.h[3], a);
                tvf[q][o8] = leaky(a);
            }
        }
        h2 tvh[2][4];
#pragma unroll
        for (int q = 0; q < 2; ++q)
#pragma unroll
            for (int p = 0; p < 4; ++p)
                tvh[q][p] = pk(tvf[q][2 * p], tvf[q][2 * p + 1]);
#pragma unroll
        for (int o = 0; o < C2; ++o) {
            F4H u;
            u.f4 = *reinterpret_cast<const float4*>(w2p + (4 * o + ch) * 256);
#pragma unroll
            for (int q = 0; q < 2; ++q) {
                float a = h2a[q][o];
                a = fdot2(tvh[q][0], u.h[0], a);
                a = fdot2(tvh[q][1], u.h[1], a);
                a = fdot2(tvh[q][2], u.h[2], a);
                a = fdot2(tvh[q][3], u.h[3], a);
                h2a[q][o] = a;
            }
        }
    }

    // ---- predicated stores ----
#pragma unroll
    for (int q = 0; q < 2; ++q) {
        if (act[q]) {
            float4* outp = reinterpret_cast<float4*>(out + (size_t)pid[q] * C2);
#pragma unroll
            for (int og = 0; og < 4; ++og) {
                float4 o;
                o.x = leaky(h2a[q][og * 4 + 0]);
                o.y = leaky(h2a[q][og * 4 + 1]);
                o.z = leaky(h2a[q][og * 4 + 2]);
                o.w = leaky(h2a[q][og * 4 + 3]);
                outp[og] = o;
            }
        }
    }
}

extern "C" void kernel_launch(void* const* d_in, const int* in_sizes, int n_in,
                              void* d_out, int out_size, void* d_ws, size_t ws_size,
                              hipStream_t stream) {
    const float* x  = (const float*)d_in[0];
    const int*  idx = (const int*)d_in[1];
    const float* W0 = (const float*)d_in[2];
    const float* b0 = (const float*)d_in[3];
    const float* W1 = (const float*)d_in[4];
    const float* b1 = (const float*)d_in[5];
    const float* W2 = (const float*)d_in[6];
    const float* b2 = (const float*)d_in[7];
    float* out = (float*)d_out;

    int n = in_sizes[1];  // N
    int blocks = (n + PPB - 1) / PPB;
    k_fused<<<blocks, BLK, 0, stream>>>(x, idx, W0, b0, W1, b1, W2, b2, out, n);
}

// Round 10
// 117.773 us; speedup vs baseline: 4.4626x; 4.4626x over previous
//
#include <hip/hip_runtime.h>
#include <hip/hip_fp16.h>

// Per-point expert-indexed MLP: h = LeakyReLU(h @ W[idx] + b[idx]) x3.
//
// R20: R1-proven 4-dispatch pipeline MINUS k_scan (3 dispatches).
// Fused-kernel arc (R13-R18) post-mortem: every variant latency-bound at
// 50-58us regardless of fences/occupancy/LDS-traffic; R1 pipeline's
// kernels+gaps ~43us beats it. So: bank R1, delete its pure-waste piece.
// k_scan (1 block, whole-GPU idle + a dispatch gap) is folded into
// k_scatter: each block re-derives its per-expert prefix from the RAW
// partials (16-thread strided sums + LDS reduce, ~31KB L2 reads/block)
// and the padded segment offsets (16-lane shfl scan). Block 0 publishes
// counts/offsets/total for k_mlp. k_hist and k_mlp byte-identical to R1.

#define L_EXP 16
#define IN0   7
#define C0    16
#define C1    32
#define C2    16
#define NEG   0.2f
#define BLK   256
#define MPT   4
#define SEGPAD (BLK * MPT)   // 1024
#define CHUNK  1024          // points per hist/scatter block
#define NBM    512           // max hist/scatter blocks (n <= 524288)

// transposed-packed fp16 weight counts (halves)
#define NW0T 2048            // 16 experts x [16 o][8 c-padded]
#define NW1T 8192            // 16 experts x [32 o][16 c]
#define NW2T 8192            // 16 experts x [16 o][32 c]
#define NWT_TOT (NW0T + NW1T + NW2T)       // 18432
#define PREPBLK (NWT_TOT / BLK)            // 72

// ws layout:
//   int [0..15]            counts per expert (written by k_scatter block 0)
//   int [16..32]           padded seg offsets, [32] = padded total
//   int [64 .. 64+16*NBM)  RAW partial hist [e][b] (k_hist; never rewritten)
//   byte 33792             hW0t: 2048 halves (4096 B)   [e][o][c0..7 pad]
//   byte 37888             hW1t: 8192 halves (16384 B)  [e][o][c0..15]
//   byte 54272             hW2t: 8192 halves (16384 B)  [e][o][c0..31]
//   int [18432 .. )        perm: pid per sorted slot (pads: poison, clamped)
#define WS_PART  64
#define WB_W0T   33792
#define WB_W1T   37888
#define WB_W2T   54272
#define WS_PERM  18432

typedef _Float16 h2 __attribute__((ext_vector_type(2)));
union F4H { float4 f4; h2 h[4]; };

__device__ __forceinline__ h2 pk(float a, float b) {
    return __builtin_bit_cast(h2, __builtin_amdgcn_cvt_pkrtz(a, b));
}

__global__ void k_hist(const int* __restrict__ idx, int n, int nblk,
                       int* __restrict__ ws,
                       const float* __restrict__ W0,
                       const float* __restrict__ W1,
                       const float* __restrict__ W2) {
    int t = threadIdx.x;
    if (blockIdx.x >= nblk) {
        // build transposed c-pair-packed fp16 weights
        int k = (blockIdx.x - nblk) * BLK + t;
        __half* hW0 = (__half*)((char*)ws + WB_W0T);
        __half* hW1 = (__half*)((char*)ws + WB_W1T);
        __half* hW2 = (__half*)((char*)ws + WB_W2T);
        if (k < NW0T) {
            int e = k >> 7, r = k & 127, o = r >> 3, c = r & 7;
            float v = (c < IN0) ? W0[e * (IN0 * C0) + c * C0 + o] : 0.0f;
            hW0[k] = __float2half(v);
        } else if (k < NW0T + NW1T) {
            int k2 = k - NW0T;
            int e = k2 >> 9, r = k2 & 511, o = r >> 4, c = r & 15;
            hW1[k2] = __float2half(W1[e * (C0 * C1) + c * C1 + o]);
        } else {
            int k2 = k - NW0T - NW1T;
            int e = k2 >> 9, r = k2 & 511, o = r >> 5, c = r & 31;
            hW2[k2] = __float2half(W2[e * (C1 * C2) + c * C2 + o]);
        }
        return;
    }
    __shared__ int bins[L_EXP];
    if (t < L_EXP) bins[t] = 0;
    __syncthreads();
    int i4 = blockIdx.x * CHUNK + t * 4;
    if (i4 + 3 < n) {
        int4 v = *reinterpret_cast<const int4*>(idx + i4);
        atomicAdd(&bins[v.x & 15], 1);
        atomicAdd(&bins[v.y & 15], 1);
        atomicAdd(&bins[v.z & 15], 1);
        atomicAdd(&bins[v.w & 15], 1);
    } else {
#pragma unroll
        for (int q = 0; q < 4; ++q)
            if (i4 + q < n) atomicAdd(&bins[idx[i4 + q] & 15], 1);
    }
    __syncthreads();
    if (t < L_EXP) ws[WS_PART + t * NBM + blockIdx.x] = bins[t];
}

__global__ void k_scatter(const int* __restrict__ idx, int n, int nblk,
                          int* __restrict__ ws) {
    __shared__ int pre_s[L_EXP][17];   // [e][j] partial prefix sums (+pad)
    __shared__ int tot_s[L_EXP][17];   // [e][j] partial totals
    __shared__ int soff[L_EXP];
    __shared__ int lcount[L_EXP];
    int t = threadIdx.x;
    int b = blockIdx.x;

    // 16 threads per expert sum the raw partials: prefix (b' < b) and total
    {
        int e = t & 15, j = t >> 4;    // j = 0..15
        int pre = 0, tot = 0;
        for (int bb = j; bb < nblk; bb += 16) {
            int v = ws[WS_PART + e * NBM + bb];
            tot += v;
            if (bb < b) pre += v;
        }
        pre_s[e][j] = pre;
        tot_s[e][j] = tot;
    }
    __syncthreads();
    if (t < L_EXP) {   // lane e: reduce, padded-scan, publish
        int pre = 0, tot = 0;
#pragma unroll
        for (int q = 0; q < 16; ++q) { pre += pre_s[t][q]; tot += tot_s[t][q]; }
        int pad = ((tot + SEGPAD - 1) / SEGPAD) * SEGPAD;
        int s = pad;
#pragma unroll
        for (int d = 1; d < L_EXP; d <<= 1) {
            int u = __shfl_up(s, d, 64);
            if (t >= d) s += u;
        }
        int segoff = s - pad;          // exclusive padded offset
        soff[t] = segoff + pre;
        lcount[t] = 0;
        if (b == 0) {
            ws[t] = tot;               // counts per expert
            ws[16 + t] = segoff;       // padded seg offsets
            if (t == L_EXP - 1) ws[32] = s;   // padded total
        }
    }
    __syncthreads();
    int i4 = b * CHUNK + t * 4;
#pragma unroll
    for (int q = 0; q < 4; ++q) {
        int i = i4 + q;
        if (i < n) {
            int e = idx[i] & 15;
            int r = atomicAdd(&lcount[e], 1);   // LDS only
            ws[WS_PERM + soff[e] + r] = i;
        }
    }
}

__device__ __forceinline__ float leaky(float a) { return fmaxf(a, NEG * a); }

__device__ __forceinline__ float fdot2(h2 a, h2 b, float c) {
    return __builtin_amdgcn_fdot2(a, b, c, false);
}

__global__ void __launch_bounds__(BLK, 2) k_mlp(
    const int* __restrict__ meta, const float* __restrict__ x,
    const float* __restrict__ b0, const float* __restrict__ b1,
    const float* __restrict__ b2, float* __restrict__ out) {
    __shared__ __align__(16) __half sW0t[C0 * 8];     // [o][c0..7]  256 B
    __shared__ __align__(16) __half sW1t[C1 * C0];    // [o][c0..15] 1 KB
    __shared__ __align__(16) __half sW2t[C2 * C1];    // [o][c0..31] 1 KB
    __shared__ __align__(16) float sB0[C0];
    __shared__ __align__(16) float sB1[C1];
    __shared__ __align__(16) float sB2[C2];

    int start = blockIdx.x * SEGPAD;
    if (start >= meta[32]) return;  // uniform

    int e = 0;
    while (start >= meta[16 + e + 1]) ++e;
    e = __builtin_amdgcn_readfirstlane(e);

    int t = threadIdx.x;
    {
        const int* w0i = (const int*)((const char*)meta + WB_W0T) + e * 64;
        const int* w1i = (const int*)((const char*)meta + WB_W1T) + e * 256;
        const int* w2i = (const int*)((const char*)meta + WB_W2T) + e * 256;
        if (t < 64) reinterpret_cast<int*>(sW0t)[t] = w0i[t];
        reinterpret_cast<int*>(sW1t)[t] = w1i[t];
        reinterpret_cast<int*>(sW2t)[t] = w2i[t];
        if (t >= 128 && t < 128 + C0) sB0[t - 128] = b0[e * C0 + (t - 128)];
        if (t >= 160 && t < 160 + C1) sB1[t - 160] = b1[e * C1 + (t - 160)];
        if (t >= 192 && t < 192 + C2) sB2[t - 192] = b2[e * C2 + (t - 192)];
    }
    __syncthreads();

    int seg = meta[16 + e];
    int cnt = meta[e];
    int j0 = start - seg + t;

    h2  xh[MPT][4];
    int pid[MPT];
    bool act[MPT];
#pragma unroll
    for (int m = 0; m < MPT; ++m) {
        int j = j0 + m * BLK;
        act[m] = (j < cnt);
        int p = meta[WS_PERM + seg + j];   // pad slots: poison ->
        pid[m] = act[m] ? p : 0;           // clamp (no divergent flow)
        const float* xp = x + (size_t)pid[m] * IN0;
        float4 a = *reinterpret_cast<const float4*>(xp);
        float4 b = *reinterpret_cast<const float4*>(xp + 3);
        xh[m][0] = pk(a.x, a.y);
        xh[m][1] = pk(a.z, a.w);
        xh[m][2] = pk(b.y, b.z);
        xh[m][3] = pk(b.w, 0.0f);  // pad c=7 (weight there is 0 too)
    }
    __builtin_amdgcn_sched_barrier(0);

    // ---- Layer 0: 7 -> 16. Per o: one b128 row (4 half2), 4 fdot2/pt ----
    float h0f[MPT][C0];
#pragma unroll
    for (int o = 0; o < C0; ++o) {
        F4H u;
        u.f4 = *reinterpret_cast<const float4*>(&sW0t[o * 8]);
#pragma unroll
        for (int m = 0; m < MPT; ++m) {
            float a = sB0[o];
            a = fdot2(xh[m][0], u.h[0], a);
            a = fdot2(xh[m][1], u.h[1], a);
            a = fdot2(xh[m][2], u.h[2], a);
            a = fdot2(xh[m][3], u.h[3], a);
            h0f[m][o] = leaky(a);
        }
        if (o == 7) __builtin_amdgcn_sched_barrier(0);  // mid-layer fence
    }
    // pack h0 into half2 pairs for layer-1 dot2
    h2 h0h[MPT][8];
#pragma unroll
    for (int m = 0; m < MPT; ++m)
#pragma unroll
        for (int p = 0; p < 8; ++p)
            h0h[m][p] = pk(h0f[m][2 * p], h0f[m][2 * p + 1]);
    __builtin_amdgcn_sched_barrier(0);

    // ---- Layers 1+2 fused; REAL loop, 8 h1-neurons per chunk ----
    float h2a[MPT][C2];
#pragma unroll
    for (int m = 0; m < MPT; ++m)
#pragma unroll
        for (int o = 0; o < C2; ++o) h2a[m][o] = sB2[o];
#pragma unroll 1
    for (int ch = 0; ch < C1 / 8; ++ch) {   // h1 neurons ch*8 .. ch*8+7
        float tvf[MPT][8];
#pragma unroll
        for (int o8 = 0; o8 < 8; ++o8) {
            int o = ch * 8 + o8;
            F4H ua, ub;
            ua.f4 = reinterpret_cast<const float4*>(&sW1t[o * C0])[0];
            ub.f4 = reinterpret_cast<const float4*>(&sW1t[o * C0])[1];
#pragma unroll
            for (int m = 0; m < MPT; ++m) {
                float a = sB1[o];
                a = fdot2(h0h[m][0], ua.h[0], a);
                a = fdot2(h0h[m][1], ua.h[1], a);
                a = fdot2(h0h[m][2], ua.h[2], a);
                a = fdot2(h0h[m][3], ua.h[3], a);
                a = fdot2(h0h[m][4], ub.h[0], a);
                a = fdot2(h0h[m][5], ub.h[1], a);
                a = fdot2(h0h[m][6], ub.h[2], a);
                a = fdot2(h0h[m][7], ub.h[3], a);
                tvf[m][o8] = leaky(a);
            }
        }
        __builtin_amdgcn_sched_barrier(0);
        h2 tvh[MPT][4];
#pragma unroll
        for (int m = 0; m < MPT; ++m)
#pragma unroll
            for (int p = 0; p < 4; ++p)
                tvh[m][p] = pk(tvf[m][2 * p], tvf[m][2 * p + 1]);
#pragma unroll
        for (int o = 0; o < C2; ++o) {
            F4H u;
            u.f4 = *reinterpret_cast<const float4*>(&sW2t[o * C1 + ch * 8]);
#pragma unroll
            for (int m = 0; m < MPT; ++m) {
                float a = h2a[m][o];
                a = fdot2(tvh[m][0], u.h[0], a);
                a = fdot2(tvh[m][1], u.h[1], a);
                a = fdot2(tvh[m][2], u.h[2], a);
                a = fdot2(tvh[m][3], u.h[3], a);
                h2a[m][o] = a;
            }
        }
        __builtin_amdgcn_sched_barrier(0);  // fence at chunk boundary
    }

    // ---- predicated stores ----
#pragma unroll
    for (int m = 0; m < MPT; ++m) {
        if (act[m]) {
            float4* outp = reinterpret_cast<float4*>(out + (size_t)pid[m] * C2);
#pragma unroll
            for (int og = 0; og < C2 / 4; ++og) {
                float4 o;
                o.x = leaky(h2a[m][og * 4 + 0]);
                o.y = leaky(h2a[m][og * 4 + 1]);
                o.z = leaky(h2a[m][og * 4 + 2]);
                o.w = leaky(h2a[m][og * 4 + 3]);
                outp[og] = o;
            }
        }
    }
}

extern "C" void kernel_launch(void* const* d_in, const int* in_sizes, int n_in,
                              void* d_out, int out_size, void* d_ws, size_t ws_size,
                              hipStream_t stream) {
    const float* x  = (const float*)d_in[0];
    const int*  idx = (const int*)d_in[1];
    const float* W0 = (const float*)d_in[2];
    const float* b0 = (const float*)d_in[3];
    const float* W1 = (const float*)d_in[4];
    const float* b1 = (const float*)d_in[5];
    const float* W2 = (const float*)d_in[6];
    const float* b2 = (const float*)d_in[7];
    float* out = (float*)d_out;

    int n = in_sizes[1];  // N
    int* ws = (int*)d_ws;

    int nblk = (n + CHUNK - 1) / CHUNK;   // <= NBM
    k_hist<<<nblk + PREPBLK, BLK, 0, stream>>>(idx, n, nblk, ws, W0, W1, W2);
    k_scatter<<<nblk, BLK, 0, stream>>>(idx, n, nblk, ws);

    int mblk = (n + L_EXP * (SEGPAD - 1) + SEGPAD - 1) / SEGPAD;
    k_mlp<<<mblk, BLK, 0, stream>>>(ws, x, b0, b1, b2, out);
}